// Round 7
// baseline (238.653 us; speedup 1.0000x reference)
//
#include <hip/hip_runtime.h>
#include <hip/hip_fp16.h>

#define N_NODES 80000
#define N_EDGES 1280000
#define IN_CH 128
#define HID 64
#define OUT_CH 32

#define BIN_BLOCKS 125   // chunk = 10240 = 20*512 exactly
#define ELLW 32          // direct-binned ELL width; P(deg>32 | Poisson(16)) ~ 1e-4
#define OVF_CAP 8192     // overflow edges (expected ~15; 500x margin)

typedef float vf2 __attribute__((ext_vector_type(2)));
typedef float vf4 __attribute__((ext_vector_type(4)));
typedef short short8 __attribute__((ext_vector_type(8)));   // 8 bf16 (4 VGPRs)
typedef float floatx4 __attribute__((ext_vector_type(4)));  // MFMA acc

// ---- bf16 pack (RNE) for MFMA staging ----
__device__ __forceinline__ unsigned bf16rn(float x) {
    unsigned u = __float_as_uint(x);
    return (u + 0x7FFFu + ((u >> 16) & 1u)) >> 16;
}
__device__ __forceinline__ unsigned packbf2(float a, float b) {
    return bf16rn(a) | (bf16rn(b) << 16);
}
// ---- f16 pack/unpack for gather tables ----
__device__ __forceinline__ float hl(unsigned u) {
    return __half2float(__ushort_as_half((unsigned short)(u & 0xFFFFu)));
}
__device__ __forceinline__ float hh(unsigned u) {
    return __half2float(__ushort_as_half((unsigned short)(u >> 16)));
}
__device__ __forceinline__ unsigned pack2h(float a, float b) {
    return (unsigned)__half_as_ushort(__float2half_rn(a)) |
           ((unsigned)__half_as_ushort(__float2half_rn(b)) << 16);
}
// clamp pad sentinel (0xFFFFFFFF) to the zero row at index N_NODES
__device__ __forceinline__ int clampid(int s) {
    unsigned v = (unsigned)s;
    return (int)(v > (unsigned)N_NODES ? (unsigned)N_NODES : v);
}

// ---------------- fused K1: direct-ELL bin (blocks 0..124) + MFMA GEMM1 ----
// bin: one pass over edges; pos = atomicAdd(cnt[dst]); pos<ELLW -> ell slot,
// else tiny overflow list. No LDS, no histogram, no counting sort.
// GEMM1: h1[n][:] = x[n] @ W1 (UNSCALED; k_meta rescales by dinv), f16 [N][64].
__global__ __launch_bounds__(512, 6) void k_bin_gemm1(
        const int* __restrict__ src, const int* __restrict__ dst,
        int* __restrict__ cnt, int* __restrict__ ell,
        int2* __restrict__ ovf, int* __restrict__ ovfcnt,
        const float* __restrict__ x, const float* __restrict__ W1,
        unsigned short* __restrict__ h1h) {
    __shared__ unsigned short smem_u[26112];  // 52224 B (GEMM path only)
    int bid = blockIdx.x, t = threadIdx.x;
    if (bid < BIN_BLOCKS) {
        // ---- bin path: 10240 edges/block, 20/thread, 4 atomics in flight ----
        const int chunk = N_EDGES / BIN_BLOCKS;  // 10240
        int e0 = bid * chunk;
        int e1 = e0 + chunk;
        for (int base = e0 + t; base < e1; base += 2048) {
            int d[4], s[4], p[4];
#pragma unroll
            for (int k = 0; k < 4; ++k) {
                d[k] = dst[base + k * 512];
                s[k] = src[base + k * 512];
            }
#pragma unroll
            for (int k = 0; k < 4; ++k) p[k] = atomicAdd(&cnt[d[k]], 1);
#pragma unroll
            for (int k = 0; k < 4; ++k) {
                if (p[k] < ELLW) {
                    ell[(size_t)d[k] * ELLW + p[k]] = s[k];
                } else {
                    int o = atomicAdd(ovfcnt, 1);
                    if (o < OVF_CAP) ovf[o] = make_int2(d[k], s[k]);
                }
            }
        }
    } else {
        // ---- MFMA GEMM1: sX [128 nodes][136] bf16, sWT [64 cols][136] bf16 ----
        unsigned short* sX = smem_u;              // 128*136
        unsigned short* sWT = smem_u + 128 * 136; // 64*136
        long long nb = (long long)(bid - BIN_BLOCKS) * 128;
        // h1h zero row (pad target for ELL gathers) -- written once
        if (bid == BIN_BLOCKS && t < 16)
            *(uint2*)&h1h[(size_t)N_NODES * 64 + t * 4] = (uint2){0u, 0u};
        // stage x -> bf16 (row-major, k contiguous)
        for (int it = 0; it < 8; ++it) {
            int idx = t + it * 512;               // 4096 float4 loads
            int node = idx >> 5, k4 = (idx & 31) * 4;
            float4 v = *(const float4*)&x[(nb + node) * IN_CH + k4];
            unsigned u0 = packbf2(v.x, v.y), u1 = packbf2(v.z, v.w);
            *(uint2*)&sX[node * 136 + k4] = (uint2){u0, u1};
        }
        // stage W1^T -> bf16 ([col][k])
        for (int it = 0; it < 4; ++it) {
            int idx = t + it * 512;               // 2048 float4 loads
            int k = idx >> 4, c4 = (idx & 15) * 4;
            float4 w = *(const float4*)&W1[k * 64 + c4];
            sWT[(c4 + 0) * 136 + k] = (unsigned short)bf16rn(w.x);
            sWT[(c4 + 1) * 136 + k] = (unsigned short)bf16rn(w.y);
            sWT[(c4 + 2) * 136 + k] = (unsigned short)bf16rn(w.z);
            sWT[(c4 + 3) * 136 + k] = (unsigned short)bf16rn(w.w);
        }
        __syncthreads();
        int wv = t >> 6, lane = t & 63;          // 8 waves, 16 nodes each
        int lm = lane & 15, q = lane >> 4;
        int m0 = wv * 16;
        floatx4 acc[4];
#pragma unroll
        for (int j = 0; j < 4; ++j) acc[j] = (floatx4){0.f, 0.f, 0.f, 0.f};
#pragma unroll
        for (int kk = 0; kk < 128; kk += 32) {
            short8 a0 = *(short8*)&sX[(m0 + lm) * 136 + kk + q * 8];
#pragma unroll
            for (int ct = 0; ct < 4; ++ct) {
                short8 bfr = *(short8*)&sWT[(ct * 16 + lm) * 136 + kk + q * 8];
                acc[ct] = __builtin_amdgcn_mfma_f32_16x16x32_bf16(a0, bfr, acc[ct], 0, 0, 0);
            }
        }
        // D layout: col = lane&15, row = q*4 + reg
#pragma unroll
        for (int ct = 0; ct < 4; ++ct)
#pragma unroll
            for (int r = 0; r < 4; ++r) {
                long long node = nb + m0 + q * 4 + r;
                int c = ct * 16 + lm;
                h1h[node * 64 + c] = __half_as_ushort(__float2half_rn(acc[ct][r]));
            }
    }
}

// ---------------- K2 (k_meta): dinv + meta + in-place h1 pre-scale ----------
// One thread per (node, uint2-column): 16 threads/node. Replaces the whole
// counting-sort kernel.
__global__ __launch_bounds__(256) void k_meta(
        const int* __restrict__ cnt, float2* __restrict__ meta,
        unsigned int* __restrict__ h1u, unsigned int* __restrict__ g2u) {
    int gid = blockIdx.x * 256 + threadIdx.x;   // 80000*16 total
    int n = gid >> 4, c = gid & 15;
    if (blockIdx.x == 0 && threadIdx.x < 16)
        g2u[(size_t)N_NODES * 16 + threadIdx.x] = 0u;  // g2 zero row
    int dg = cnt[n];
    float dv = rsqrtf((float)(dg + 1));         // +1 self loop
    if (c == 0) meta[n] = make_float2(dv, (float)dg);
    uint2 u = *(uint2*)&h1u[(size_t)n * 32 + 2 * c];
    u.x = pack2h(dv * hl(u.x), dv * hh(u.x));
    u.y = pack2h(dv * hl(u.y), dv * hh(u.y));
    *(uint2*)&h1u[(size_t)n * 32 + 2 * c] = u;
}

// ---------------- agg layer 1 + fused GEMM2 (ELL32, 2-round-trip chain) -----
// 2 nodes/wave, 2 streams x 16 lanes x uint2 per node.
// Round 1: 8x int4 ELL loads + meta + self row + bias (all from n alone).
// Round 2: 16 gathers, unconditional (pads clamp to zero row). Residual
// (deg>32, ~8 nodes total) scans the tiny overflow list.
__global__ __launch_bounds__(256) void k_agg64(
        const unsigned int* __restrict__ h1u, const int* __restrict__ ell,
        const int2* __restrict__ ovf, const int* __restrict__ ovfcnt,
        const float2* __restrict__ meta, const float* __restrict__ b1,
        const float* __restrict__ W2, unsigned int* __restrict__ g2u) {
    __shared__ float sW2[64 * 32];     // 8 KB, staged once per block
    __shared__ float sH2[4][2][64];    // per-wave, per-node h2 row
    int t = threadIdx.x;
    for (int i = t * 2; i < 64 * 32; i += 512)
        *(vf2*)&sW2[i] = *(const vf2*)&W2[i];

    int wv = t >> 6, lane = t & 63;
    int nd = lane >> 5;          // which of the wave's 2 nodes
    int q  = (lane >> 4) & 1;    // edge stream within node (slot parity)
    int fo = lane & 15;          // uint2 index -> feats 4fo..4fo+3
    int col = lane & 31;
    int n = blockIdx.x * 8 + wv * 2 + nd;

    // ---- round 1: everything computable from n, issued together ----
    float2 mt = meta[n];
    float dn = mt.x;
    int dg = (int)mt.y;
    uint2 un = *(const uint2*)&h1u[(size_t)n * 32 + 2 * fo];  // self row
    float4 bb = *(const float4*)&b1[4 * fo];
    const int* er = ell + (size_t)n * ELLW;
    int4 w0 = *(const int4*)&er[0];
    int4 w1 = *(const int4*)&er[4];
    int4 w2 = *(const int4*)&er[8];
    int4 w3 = *(const int4*)&er[12];
    int4 w4 = *(const int4*)&er[16];
    int4 w5 = *(const int4*)&er[20];
    int4 w6 = *(const int4*)&er[24];
    int4 w7 = *(const int4*)&er[28];
    int ss[16];
    ss[0]  = q ? w0.y : w0.x;  ss[1]  = q ? w0.w : w0.z;
    ss[2]  = q ? w1.y : w1.x;  ss[3]  = q ? w1.w : w1.z;
    ss[4]  = q ? w2.y : w2.x;  ss[5]  = q ? w2.w : w2.z;
    ss[6]  = q ? w3.y : w3.x;  ss[7]  = q ? w3.w : w3.z;
    ss[8]  = q ? w4.y : w4.x;  ss[9]  = q ? w4.w : w4.z;
    ss[10] = q ? w5.y : w5.x;  ss[11] = q ? w5.w : w5.z;
    ss[12] = q ? w6.y : w6.x;  ss[13] = q ? w6.w : w6.z;
    ss[14] = q ? w7.y : w7.x;  ss[15] = q ? w7.w : w7.z;
    // ---- round 2: 16 gathers, unconditional (pads -> zero row) ----
    float ax = 0.f, ay = 0.f, az = 0.f, aw = 0.f;
#pragma unroll
    for (int i = 0; i < 16; ++i) {
        int s = clampid(ss[i]);
        uint2 u = *(const uint2*)&h1u[(size_t)s * 32 + 2 * fo];
        ax += hl(u.x); ay += hh(u.x); az += hl(u.y); aw += hh(u.y);
    }
    // combine the node's two streams: lanes 0..15 (nd=0) / 32..47 (nd=1)
    ax += __shfl_down(ax, 16); ay += __shfl_down(ay, 16);
    az += __shfl_down(az, 16); aw += __shfl_down(aw, 16);
    __syncthreads();   // sW2 staged; uniform for all threads
    if (q == 0) {
        // residual (deg > 32): scan tiny overflow list (~15 entries total)
        if (dg > ELLW) {
            int m = min(ovfcnt[0], OVF_CAP);
            for (int i = 0; i < m; ++i) {
                int2 oe = ovf[i];
                if (oe.x == n) {
                    uint2 u = *(const uint2*)&h1u[(size_t)oe.y * 32 + 2 * fo];
                    ax += hl(u.x); ay += hh(u.x); az += hl(u.y); aw += hh(u.y);
                }
            }
        }
        // self loop (table pre-scaled) + bias + relu
        ax += hl(un.x); ay += hh(un.x); az += hl(un.y); aw += hh(un.y);
        vf4 h2v = {fmaxf(dn * ax + bb.x, 0.f), fmaxf(dn * ay + bb.y, 0.f),
                   fmaxf(dn * az + bb.z, 0.f), fmaxf(dn * aw + bb.w, 0.f)};
        *(vf4*)&sH2[wv][nd][4 * fo] = h2v;
    }
    __syncthreads();
    // fused GEMM2: each lane computes one (node, col) of g2' = dn * (h2 @ W2)
    int nd2 = lane >> 5;   // == nd
    const float* hrow = sH2[wv][nd2];
    float g = 0.f;
#pragma unroll
    for (int k = 0; k < 64; ++k) g += hrow[k] * sW2[k * 32 + col];
    g *= dn;               // pre-scale table by dinv[n]
    float g1 = __shfl_down(g, 1);
    float g2v = __shfl_down(g, 2);
    float g3v = __shfl_down(g, 3);
    if ((lane & 3) == 0) {
        uint2 p = {pack2h(g, g1), pack2h(g2v, g3v)};
        *(uint2*)&g2u[(size_t)n * 16 + (col >> 1)] = p;
    }
}

// ---------------- agg layer 2: F=32, pre-scaled f16 table, ELL32 -------------
// 8 streams x 8 lanes x uint2 (64 B row); 4 slots/stream; pads clamp to zero
// row; residual via overflow-list scan (rare).
__global__ __launch_bounds__(256) void k_agg32(
        const unsigned int* __restrict__ g2u, const int* __restrict__ ell,
        const int2* __restrict__ ovf, const int* __restrict__ ovfcnt,
        const float2* __restrict__ meta, const float* __restrict__ b2,
        float* __restrict__ outp) {
    int n = blockIdx.x * 4 + (threadIdx.x >> 6);
    int lane = threadIdx.x & 63;
    int oc = lane >> 3, fo = lane & 7;  // stream, uint2-column (feats 4fo..4fo+3)
    float2 mt = meta[n];
    float dn = mt.x;
    int dg = (int)mt.y;
    uint2 un = *(const uint2*)&g2u[(size_t)n * 16 + 2 * fo];  // self row
    const int* er = ell + (size_t)n * ELLW;
    int s0 = clampid(er[oc]);
    int s1 = clampid(er[oc + 8]);
    int s2 = clampid(er[oc + 16]);
    int s3 = clampid(er[oc + 24]);
    uint2 u0 = *(const uint2*)&g2u[(size_t)s0 * 16 + 2 * fo];
    uint2 u1 = *(const uint2*)&g2u[(size_t)s1 * 16 + 2 * fo];
    uint2 u2 = *(const uint2*)&g2u[(size_t)s2 * 16 + 2 * fo];
    uint2 u3 = *(const uint2*)&g2u[(size_t)s3 * 16 + 2 * fo];
    float ax, ay, az, aw;
    ax  = hl(u0.x); ay  = hh(u0.x); az  = hl(u0.y); aw  = hh(u0.y);
    ax += hl(u1.x); ay += hh(u1.x); az += hl(u1.y); aw += hh(u1.y);
    ax += hl(u2.x); ay += hh(u2.x); az += hl(u2.y); aw += hh(u2.y);
    ax += hl(u3.x); ay += hh(u3.x); az += hl(u3.y); aw += hh(u3.y);
    ax += __shfl_down(ax, 32); ay += __shfl_down(ay, 32);
    az += __shfl_down(az, 32); aw += __shfl_down(aw, 32);
    ax += __shfl_down(ax, 16); ay += __shfl_down(ay, 16);
    az += __shfl_down(az, 16); aw += __shfl_down(aw, 16);
    ax += __shfl_down(ax, 8);  ay += __shfl_down(ay, 8);
    az += __shfl_down(az, 8);  aw += __shfl_down(aw, 8);
    if (oc == 0) {
        if (dg > ELLW) {        // residual: scan tiny overflow list
            int m = min(ovfcnt[0], OVF_CAP);
            for (int i = 0; i < m; ++i) {
                int2 oe = ovf[i];
                if (oe.x == n) {
                    uint2 u = *(const uint2*)&g2u[(size_t)oe.y * 16 + 2 * fo];
                    ax += hl(u.x); ay += hh(u.x); az += hl(u.y); aw += hh(u.y);
                }
            }
        }
        ax += hl(un.x); ay += hh(un.x);   // self loop (table pre-scaled)
        az += hl(un.y); aw += hh(un.y);
        float4 bbv = *(const float4*)&b2[4 * fo];
        vf4 o = {dn * ax + bbv.x, dn * ay + bbv.y, dn * az + bbv.z, dn * aw + bbv.w};
        __builtin_nontemporal_store(o, (vf4*)&outp[(size_t)n * 32 + 4 * fo]);
    }
}

static inline size_t align256(size_t x) { return (x + 255) & ~(size_t)255; }

extern "C" void kernel_launch(void* const* d_in, const int* in_sizes, int n_in,
                              void* d_out, int out_size, void* d_ws, size_t ws_size,
                              hipStream_t stream) {
    const float* x  = (const float*)d_in[0];
    const int*   ei = (const int*)d_in[1];
    const float* W1 = (const float*)d_in[2];
    const float* b1 = (const float*)d_in[3];
    const float* W2 = (const float*)d_in[4];
    const float* b2 = (const float*)d_in[5];
    float* out = (float*)d_out;

    const int* src = ei;
    const int* dst = ei + N_EDGES;

    // workspace layout (~27 MB)
    char* ws = (char*)d_ws;
    size_t off = 0;
    int* cnt = (int*)(ws + off);               off = align256(off + (size_t)(N_NODES + 64) * 4);
    int* ovfcnt = cnt + N_NODES;               // zeroed with cnt
    int2* ovf = (int2*)(ws + off);             off = align256(off + (size_t)OVF_CAP * 8);
    int* ell = (int*)(ws + off);               off = align256(off + (size_t)N_NODES * ELLW * 4);
    float2* meta = (float2*)(ws + off);        off = align256(off + (size_t)N_NODES * 8);
    // +1 zero row (index N_NODES) for ELL pad gathers
    unsigned short* h1h = (unsigned short*)(ws + off);
                                               off = align256(off + (size_t)(N_NODES + 1) * 64 * 2);
    // g2u must NOT alias h1h: agg64 writes g2 while other waves still gather h1.
    unsigned int* g2u = (unsigned int*)(ws + off);
                                               off = align256(off + (size_t)(N_NODES + 1) * 16 * 4);

    (void)hipMemsetAsync(cnt, 0, (size_t)(N_NODES + 64) * 4, stream);
    (void)hipMemsetAsync(ell, 0xFF, (size_t)N_NODES * ELLW * 4, stream);  // pad sentinel
    k_bin_gemm1<<<BIN_BLOCKS + N_NODES / 128, 512, 0, stream>>>(src, dst, cnt, ell,
                                                                ovf, ovfcnt, x, W1, h1h);
    k_meta<<<N_NODES * 16 / 256, 256, 0, stream>>>(cnt, meta, (unsigned int*)h1h, g2u);
    k_agg64<<<N_NODES / 8, 256, 0, stream>>>((const unsigned int*)h1h, ell, ovf, ovfcnt,
                                             meta, b1, W2, g2u);
    k_agg32<<<N_NODES / 4, 256, 0, stream>>>(g2u, ell, ovf, ovfcnt, meta, b2, out);
}

// Round 8
// 183.328 us; speedup vs baseline: 1.3018x; 1.3018x over previous
//
#include <hip/hip_runtime.h>
#include <hip/hip_fp16.h>

#define N_NODES 80000
#define N_EDGES 1280000
#define IN_CH 128
#define HID 64
#define OUT_CH 32

#define NBUCK 625      // 128 dst-nodes per bucket; 625*128 == 80000
#define CAP 3072       // bucket capacity; Poisson(mean=2048) -> +20 sigma safe
#define BIN_BLOCKS 128
#define ELLW 24        // ELL width: covers deg<=24 (~98% of Poisson(16) nodes)

typedef float vf2 __attribute__((ext_vector_type(2)));
typedef float vf4 __attribute__((ext_vector_type(4)));
typedef short short8 __attribute__((ext_vector_type(8)));   // 8 bf16 (4 VGPRs)
typedef float floatx4 __attribute__((ext_vector_type(4)));  // MFMA acc

// ---- bf16 pack (RNE) for MFMA staging ----
__device__ __forceinline__ unsigned bf16rn(float x) {
    unsigned u = __float_as_uint(x);
    return (u + 0x7FFFu + ((u >> 16) & 1u)) >> 16;
}
__device__ __forceinline__ unsigned packbf2(float a, float b) {
    return bf16rn(a) | (bf16rn(b) << 16);
}
// ---- f16 pack/unpack for gather tables ----
__device__ __forceinline__ float hl(unsigned u) {
    return __half2float(__ushort_as_half((unsigned short)(u & 0xFFFFu)));
}
__device__ __forceinline__ float hh(unsigned u) {
    return __half2float(__ushort_as_half((unsigned short)(u >> 16)));
}
__device__ __forceinline__ unsigned pack2h(float a, float b) {
    return (unsigned)__half_as_ushort(__float2half_rn(a)) |
           ((unsigned)__half_as_ushort(__float2half_rn(b)) << 16);
}

// ---------------- fused K1: bin (blocks 0..127) + MFMA GEMM1 (blocks 128..752) ----
// Bin path: dst chunk cached in registers across both passes (one edge-list
// read instead of two); batched load issue for ILP.
// GEMM path: staging loads batch-issued into registers (8 float4 in flight)
// before the convert+LDS-store pass -- raises outstanding loads ~8x.
__global__ __launch_bounds__(512, 6) void k_bin_gemm1(
        const int* __restrict__ src, const int* __restrict__ dst,
        int* __restrict__ gcur, unsigned int* __restrict__ binned,
        const float* __restrict__ x, const float* __restrict__ W1,
        unsigned short* __restrict__ h1h) {
    __shared__ unsigned short smem_u[26112];  // 52224 B
    int bid = blockIdx.x, t = threadIdx.x;
    if (bid < BIN_BLOCKS) {
        // ---- bin path ----
        int* hist = (int*)smem_u;
        int* lcur = hist + NBUCK;
        const int chunk = N_EDGES / BIN_BLOCKS;  // 10000
        int e0 = bid * chunk;
        int e1 = e0 + chunk;
        for (int i = t; i < NBUCK; i += 512) hist[i] = 0;
        __syncthreads();
        // load this thread's <=20 dst values into registers (batched)
        int dv[20];
#pragma unroll
        for (int r = 0; r < 20; ++r) {
            int e = e0 + t + r * 512;
            dv[r] = (e < e1) ? dst[e] : -1;
        }
#pragma unroll
        for (int r = 0; r < 20; ++r)
            if (dv[r] >= 0) atomicAdd(&hist[dv[r] >> 7], 1);
        __syncthreads();
        for (int i = t; i < NBUCK; i += 512) {
            int h = hist[i];
            lcur[i] = h ? atomicAdd(&gcur[i], h) : 0;
        }
        __syncthreads();
        // scatter pass: src loads batched in groups of 4; dst from registers
#pragma unroll
        for (int r0 = 0; r0 < 20; r0 += 4) {
            int sv[4];
#pragma unroll
            for (int k = 0; k < 4; ++k) {
                int e = e0 + t + (r0 + k) * 512;
                sv[k] = (e < e1) ? src[e] : 0;
            }
#pragma unroll
            for (int k = 0; k < 4; ++k) {
                int d = dv[r0 + k];
                if (d >= 0) {
                    int bk = d >> 7;
                    int pos = atomicAdd(&lcur[bk], 1);
                    if (pos < CAP)
                        binned[(size_t)bk * CAP + pos] =
                            (unsigned int)sv[k] | ((unsigned int)(d & 127) << 17);
                }
            }
        }
    } else {
        // ---- MFMA GEMM1: sX [128 nodes][136] bf16, sWT [64 cols][136] bf16 ----
        unsigned short* sX = smem_u;              // 128*136
        unsigned short* sWT = smem_u + 128 * 136; // 64*136
        long long nb = (long long)(bid - BIN_BLOCKS) * 128;
        // h1h zero row (pad target for ELL gathers) -- written once
        if (bid == BIN_BLOCKS && t < 16)
            *(uint2*)&h1h[(size_t)N_NODES * 64 + t * 4] = (uint2){0u, 0u};
        // stage x -> bf16: batch-issue all 8 loads, then convert+store
        {
            float4 v[8];
#pragma unroll
            for (int it = 0; it < 8; ++it) {
                int idx = t + it * 512;
                int node = idx >> 5, k4 = (idx & 31) * 4;
                v[it] = *(const float4*)&x[(nb + node) * IN_CH + k4];
            }
#pragma unroll
            for (int it = 0; it < 8; ++it) {
                int idx = t + it * 512;
                int node = idx >> 5, k4 = (idx & 31) * 4;
                *(uint2*)&sX[node * 136 + k4] =
                    (uint2){packbf2(v[it].x, v[it].y), packbf2(v[it].z, v[it].w)};
            }
        }
        // stage W1^T -> bf16 ([col][k]): batch-issue 4 loads
        {
            float4 w[4];
#pragma unroll
            for (int it = 0; it < 4; ++it) {
                int idx = t + it * 512;
                int k = idx >> 4, c4 = (idx & 15) * 4;
                w[it] = *(const float4*)&W1[k * 64 + c4];
            }
#pragma unroll
            for (int it = 0; it < 4; ++it) {
                int idx = t + it * 512;
                int k = idx >> 4, c4 = (idx & 15) * 4;
                sWT[(c4 + 0) * 136 + k] = (unsigned short)bf16rn(w[it].x);
                sWT[(c4 + 1) * 136 + k] = (unsigned short)bf16rn(w[it].y);
                sWT[(c4 + 2) * 136 + k] = (unsigned short)bf16rn(w[it].z);
                sWT[(c4 + 3) * 136 + k] = (unsigned short)bf16rn(w[it].w);
            }
        }
        __syncthreads();
        int wv = t >> 6, lane = t & 63;          // 8 waves, 16 nodes each
        int lm = lane & 15, q = lane >> 4;
        int m0 = wv * 16;
        floatx4 acc[4];
#pragma unroll
        for (int j = 0; j < 4; ++j) acc[j] = (floatx4){0.f, 0.f, 0.f, 0.f};
#pragma unroll
        for (int kk = 0; kk < 128; kk += 32) {
            short8 a0 = *(short8*)&sX[(m0 + lm) * 136 + kk + q * 8];
#pragma unroll
            for (int ct = 0; ct < 4; ++ct) {
                short8 bfr = *(short8*)&sWT[(ct * 16 + lm) * 136 + kk + q * 8];
                acc[ct] = __builtin_amdgcn_mfma_f32_16x16x32_bf16(a0, bfr, acc[ct], 0, 0, 0);
            }
        }
        // D layout: col = lane&15, row = q*4 + reg
#pragma unroll
        for (int ct = 0; ct < 4; ++ct)
#pragma unroll
            for (int r = 0; r < 4; ++r) {
                long long node = nb + m0 + q * 4 + r;
                int c = ct * 16 + lm;
                h1h[node * 64 + c] = __half_as_ushort(__float2half_rn(acc[ct][r]));
            }
    }
}

// ---------------- K2: counting sort -> CSR + ELL + meta + h1 pre-scale --------
// binned chunk cached in registers across count + scatter passes.
__global__ __launch_bounds__(256) void k_csr(const unsigned int* __restrict__ binned,
                                             const int* __restrict__ cnt,
                                             int* __restrict__ csr,
                                             int* __restrict__ ell,
                                             int2* __restrict__ rse,
                                             float2* __restrict__ meta,
                                             unsigned int* __restrict__ h1u,
                                             unsigned int* __restrict__ g2u) {
    __shared__ int deg[128];
    __shared__ int scan[128];
    __shared__ int cur[128];
    __shared__ int rst[128];
    __shared__ float sdinv[128];
    int bk = blockIdx.x, t = threadIdx.x;
    int n_e = min(cnt[bk], CAP);
    const unsigned int* eb = binned + (size_t)bk * CAP;
    // g2u zero row (pad target for ELL gathers in agg32)
    if (bk == 0 && t < 16) g2u[(size_t)N_NODES * 16 + t] = 0u;
    if (t < 128) deg[t] = 0;
    __syncthreads();
    // cache this thread's <=12 packed-edge words (CAP/256 = 12), batched
    unsigned int pv[12];
#pragma unroll
    for (int r = 0; r < 12; ++r) {
        int i = t + r * 256;
        pv[r] = (i < n_e) ? eb[i] : 0xFFFFFFFFu;
    }
#pragma unroll
    for (int r = 0; r < 12; ++r)
        if (pv[r] != 0xFFFFFFFFu) atomicAdd(&deg[pv[r] >> 17], 1);
    __syncthreads();
    if (t < 128) scan[t] = deg[t];
    __syncthreads();
    for (int off = 1; off < 128; off <<= 1) {
        int v = (t < 128 && t >= off) ? scan[t - off] : 0;
        __syncthreads();
        if (t < 128) scan[t] += v;
        __syncthreads();
    }
    if (t < 128) {
        int incl = scan[t];
        int s = incl - deg[t];
        cur[t] = s;
        rst[t] = s;
        int n = bk * 128 + t;
        int base = bk * CAP;
        rse[n] = make_int2(base + s, base + incl);
        float dv = rsqrtf((float)(deg[t] + 1));  // +1 self loop
        meta[n] = make_float2(dv, (float)deg[t]);
        sdinv[t] = dv;
    }
    // ELL pad fill (coalesced; scatter overwrites valid slots after barrier)
    int* eb_ell = ell + (size_t)bk * 128 * ELLW;
    for (int i = t; i < 128 * ELLW; i += 256) eb_ell[i] = N_NODES;
    __syncthreads();
#pragma unroll
    for (int r = 0; r < 12; ++r) {
        unsigned int p = pv[r];
        if (p != 0xFFFFFFFFu) {
            int dL = p >> 17;
            int pos = atomicAdd(&cur[dL], 1);
            int s = (int)(p & 0x1FFFF);
            csr[bk * CAP + pos] = s;
            int lp = pos - rst[dL];
            if (lp < ELLW) eb_ell[dL * ELLW + lp] = s;
        }
    }
    // in-place h1 rescale for this bucket's contiguous 128 rows (16 KB)
    size_t rbase = (size_t)bk * 128 * 32;   // uints
    for (int i = t; i < 128 * 16; i += 256) {
        int row = i >> 4, c = i & 15;
        uint2 u = *(uint2*)&h1u[rbase + (size_t)row * 32 + 2 * c];
        float dv = sdinv[row];
        u.x = pack2h(dv * hl(u.x), dv * hh(u.x));
        u.y = pack2h(dv * hl(u.y), dv * hh(u.y));
        *(uint2*)&h1u[rbase + (size_t)row * 32 + 2 * c] = u;
    }
}

// ---------------- agg layer 1 + fused GEMM2 (ELL, 2-round-trip chain) --------
// 2 nodes/wave, 2 streams x 16 lanes x uint2 per node.
// Round 1 (all independent, addresses computable from n): 6x int4 ELL loads,
// meta, self row, bias. Round 2: 12 gathers, unconditional adds (pads hit the
// zero row). Residual (deg>24, ~2%) falls back to rse+csr inside the branch.
__global__ __launch_bounds__(256) void k_agg64(
        const unsigned int* __restrict__ h1u, const int* __restrict__ ell,
        const int* __restrict__ csr, const int2* __restrict__ rse,
        const float2* __restrict__ meta, const float* __restrict__ b1,
        const float* __restrict__ W2, unsigned int* __restrict__ g2u) {
    __shared__ float sW2[64 * 32];     // 8 KB, staged once per block
    __shared__ float sH2[4][2][64];    // per-wave, per-node h2 row
    int t = threadIdx.x;
    for (int i = t * 2; i < 64 * 32; i += 512)
        *(vf2*)&sW2[i] = *(const vf2*)&W2[i];

    int wv = t >> 6, lane = t & 63;
    int nd = lane >> 5;          // which of the wave's 2 nodes
    int q  = (lane >> 4) & 1;    // edge stream within node (slot parity)
    int fo = lane & 15;          // uint2 index -> feats 4fo..4fo+3
    int col = lane & 31;
    int n = blockIdx.x * 8 + wv * 2 + nd;

    // ---- round 1: everything computable from n, issued together ----
    float2 mt = meta[n];
    float dn = mt.x;
    int dg = (int)mt.y;
    uint2 un = *(const uint2*)&h1u[(size_t)n * 32 + 2 * fo];  // self row
    float4 bb = *(const float4*)&b1[4 * fo];
    const int* er = ell + (size_t)n * ELLW;
    int4 w0 = *(const int4*)&er[0];
    int4 w1 = *(const int4*)&er[4];
    int4 w2 = *(const int4*)&er[8];
    int4 w3 = *(const int4*)&er[12];
    int4 w4 = *(const int4*)&er[16];
    int4 w5 = *(const int4*)&er[20];
    int ss[12];
    ss[0]  = q ? w0.y : w0.x;  ss[1]  = q ? w0.w : w0.z;
    ss[2]  = q ? w1.y : w1.x;  ss[3]  = q ? w1.w : w1.z;
    ss[4]  = q ? w2.y : w2.x;  ss[5]  = q ? w2.w : w2.z;
    ss[6]  = q ? w3.y : w3.x;  ss[7]  = q ? w3.w : w3.z;
    ss[8]  = q ? w4.y : w4.x;  ss[9]  = q ? w4.w : w4.z;
    ss[10] = q ? w5.y : w5.x;  ss[11] = q ? w5.w : w5.z;
    // ---- round 2: 12 gathers, unconditional (pads -> zero row) ----
    float ax = 0.f, ay = 0.f, az = 0.f, aw = 0.f;
#pragma unroll
    for (int i = 0; i < 12; ++i) {
        uint2 u = *(const uint2*)&h1u[(size_t)ss[i] * 32 + 2 * fo];
        ax += hl(u.x); ay += hh(u.x); az += hl(u.y); aw += hh(u.y);
    }
    // residual (deg > 24; ~2% of nodes) -- only here do we touch rse/csr
    if (dg > ELLW) {
        int2 rb = rse[n];
        for (int e = rb.x + ELLW + q; e < rb.y; e += 2) {
            int s = csr[e];
            uint2 u = *(const uint2*)&h1u[(size_t)s * 32 + 2 * fo];
            ax += hl(u.x); ay += hh(u.x); az += hl(u.y); aw += hh(u.y);
        }
    }
    // combine the node's two streams: lanes 0..15 (nd=0) / 32..47 (nd=1)
    ax += __shfl_down(ax, 16); ay += __shfl_down(ay, 16);
    az += __shfl_down(az, 16); aw += __shfl_down(aw, 16);
    __syncthreads();   // sW2 staged; uniform for all threads
    if (q == 0) {
        // self loop (table pre-scaled) + bias + relu
        ax += hl(un.x); ay += hh(un.x); az += hl(un.y); aw += hh(un.y);
        vf4 h2v = {fmaxf(dn * ax + bb.x, 0.f), fmaxf(dn * ay + bb.y, 0.f),
                   fmaxf(dn * az + bb.z, 0.f), fmaxf(dn * aw + bb.w, 0.f)};
        *(vf4*)&sH2[wv][nd][4 * fo] = h2v;
    }
    __syncthreads();
    // fused GEMM2: each lane computes one (node, col) of g2' = dn * (h2 @ W2)
    int nd2 = lane >> 5;   // == nd
    const float* hrow = sH2[wv][nd2];
    float g = 0.f;
#pragma unroll
    for (int k = 0; k < 64; ++k) g += hrow[k] * sW2[k * 32 + col];
    g *= dn;               // pre-scale table by dinv[n]
    float g1 = __shfl_down(g, 1);
    float g2v = __shfl_down(g, 2);
    float g3v = __shfl_down(g, 3);
    if ((lane & 3) == 0) {
        uint2 p = {pack2h(g, g1), pack2h(g2v, g3v)};
        *(uint2*)&g2u[(size_t)n * 16 + (col >> 1)] = p;
    }
}

// ---------------- agg layer 2: F=32, pre-scaled f16 table, ELL ----------------
// 8 streams x 8 lanes x uint2 (64 B row). Slots oc, oc+8, oc+16 from ELL;
// unconditional adds (pads -> zero row); residual via rse/csr (rare).
__global__ __launch_bounds__(256) void k_agg32(
        const unsigned int* __restrict__ g2u, const int* __restrict__ ell,
        const int* __restrict__ csr, const int2* __restrict__ rse,
        const float2* __restrict__ meta, const float* __restrict__ b2,
        float* __restrict__ outp) {
    int n = blockIdx.x * 4 + (threadIdx.x >> 6);
    int lane = threadIdx.x & 63;
    int oc = lane >> 3, fo = lane & 7;  // stream, uint2-column (feats 4fo..4fo+3)
    float2 mt = meta[n];
    float dn = mt.x;
    int dg = (int)mt.y;
    uint2 un = *(const uint2*)&g2u[(size_t)n * 16 + 2 * fo];  // self row
    const int* er = ell + (size_t)n * ELLW;
    int s0 = er[oc];
    int s1 = er[oc + 8];
    int s2 = er[oc + 16];
    uint2 u0 = *(const uint2*)&g2u[(size_t)s0 * 16 + 2 * fo];
    uint2 u1 = *(const uint2*)&g2u[(size_t)s1 * 16 + 2 * fo];
    uint2 u2 = *(const uint2*)&g2u[(size_t)s2 * 16 + 2 * fo];
    float ax, ay, az, aw;
    ax  = hl(u0.x); ay  = hh(u0.x); az  = hl(u0.y); aw  = hh(u0.y);
    ax += hl(u1.x); ay += hh(u1.x); az += hl(u1.y); aw += hh(u1.y);
    ax += hl(u2.x); ay += hh(u2.x); az += hl(u2.y); aw += hh(u2.y);
    if (dg > ELLW) {
        int2 rb = rse[n];
        for (int e = rb.x + ELLW + oc; e < rb.y; e += 8) {
            int s = csr[e];
            uint2 u = *(const uint2*)&g2u[(size_t)s * 16 + 2 * fo];
            ax += hl(u.x); ay += hh(u.x); az += hl(u.y); aw += hh(u.y);
        }
    }
    ax += __shfl_down(ax, 32); ay += __shfl_down(ay, 32);
    az += __shfl_down(az, 32); aw += __shfl_down(aw, 32);
    ax += __shfl_down(ax, 16); ay += __shfl_down(ay, 16);
    az += __shfl_down(az, 16); aw += __shfl_down(aw, 16);
    ax += __shfl_down(ax, 8);  ay += __shfl_down(ay, 8);
    az += __shfl_down(az, 8);  aw += __shfl_down(aw, 8);
    if (oc == 0) {
        ax += hl(un.x); ay += hh(un.x);   // self loop (table pre-scaled)
        az += hl(un.y); aw += hh(un.y);
        float4 bbv = *(const float4*)&b2[4 * fo];
        vf4 o = {dn * ax + bbv.x, dn * ay + bbv.y, dn * az + bbv.z, dn * aw + bbv.w};
        __builtin_nontemporal_store(o, (vf4*)&outp[(size_t)n * 32 + 4 * fo]);
    }
}

static inline size_t align256(size_t x) { return (x + 255) & ~(size_t)255; }

extern "C" void kernel_launch(void* const* d_in, const int* in_sizes, int n_in,
                              void* d_out, int out_size, void* d_ws, size_t ws_size,
                              hipStream_t stream) {
    const float* x  = (const float*)d_in[0];
    const int*   ei = (const int*)d_in[1];
    const float* W1 = (const float*)d_in[2];
    const float* b1 = (const float*)d_in[3];
    const float* W2 = (const float*)d_in[4];
    const float* b2 = (const float*)d_in[5];
    float* out = (float*)d_out;

    const int* src = ei;
    const int* dst = ei + N_EDGES;

    // workspace layout (~40 MB)
    char* ws = (char*)d_ws;
    size_t off = 0;
    int* gcur = (int*)(ws + off);              off = align256(off + NBUCK * 4);
    unsigned int* binned = (unsigned int*)(ws + off);
                                               off = align256(off + (size_t)NBUCK * CAP * 4);
    int* csr = (int*)(ws + off);               off = align256(off + (size_t)NBUCK * CAP * 4);
    int* ell = (int*)(ws + off);               off = align256(off + (size_t)N_NODES * ELLW * 4);
    int2* rse = (int2*)(ws + off);             off = align256(off + (size_t)N_NODES * 8);
    float2* meta = (float2*)(ws + off);        off = align256(off + (size_t)N_NODES * 8);
    // +1 zero row (index N_NODES) for ELL pad gathers
    unsigned short* h1h = (unsigned short*)(ws + off);
                                               off = align256(off + (size_t)(N_NODES + 1) * 64 * 2);
    // g2u must NOT alias h1h: agg64 writes g2 while other waves still gather h1.
    unsigned int* g2u = (unsigned int*)(ws + off);
                                               off = align256(off + (size_t)(N_NODES + 1) * 16 * 4);

    (void)hipMemsetAsync(gcur, 0, NBUCK * 4, stream);
    k_bin_gemm1<<<BIN_BLOCKS + N_NODES / 128, 512, 0, stream>>>(src, dst, gcur, binned,
                                                                x, W1, h1h);
    k_csr<<<NBUCK, 256, 0, stream>>>(binned, gcur, csr, ell, rse, meta,
                                     (unsigned int*)h1h, g2u);
    k_agg64<<<N_NODES / 8, 256, 0, stream>>>((const unsigned int*)h1h, ell, csr, rse,
                                             meta, b1, W2, g2u);
    k_agg32<<<N_NODES / 4, 256, 0, stream>>>(g2u, ell, csr, rse, meta, b2, out);
}